// Round 2
// baseline (22830.551 us; speedup 1.0000x reference)
//
#include <hip/hip_runtime.h>
#include <hip/hip_bf16.h>
#include <hip/hip_cooperative_groups.h>

namespace cg = cooperative_groups;

#define B_ 128
#define T_ 512
#define E_ 256
#define H_ 1024
#define G_ 4096           // 4*H
#define KTOT 1280         // E + H

typedef _Float16 f16x8 __attribute__((ext_vector_type(8)));
typedef float f32x4 __attribute__((ext_vector_type(4)));

// ---------------- JAX threefry2x32 (exact) ----------------
__device__ __forceinline__ void threefry2x32(unsigned k0, unsigned k1,
                                             unsigned x0, unsigned x1,
                                             unsigned& o0, unsigned& o1) {
  unsigned k2 = k0 ^ k1 ^ 0x1BD11BDAu;
  unsigned v0 = x0 + k0, v1 = x1 + k1;
#define RND(r) { v0 += v1; v1 = (v1 << (r)) | (v1 >> (32 - (r))); v1 ^= v0; }
  RND(13) RND(15) RND(26) RND(6)   v0 += k1; v1 += k2 + 1u;
  RND(17) RND(29) RND(16) RND(24)  v0 += k2; v1 += k0 + 2u;
  RND(13) RND(15) RND(26) RND(6)   v0 += k0; v1 += k1 + 3u;
  RND(17) RND(29) RND(16) RND(24)  v0 += k1; v1 += k2 + 4u;
  RND(13) RND(15) RND(26) RND(6)   v0 += k2; v1 += k0 + 5u;
#undef RND
  o0 = v0; o1 = v1;
}

// JAX threefry_partitionable (default since 0.4.30), bit_width=32:
// bits(i) = b1 ^ b2 where (b1,b2) = threefry2x32(key, hi32(i)=0, lo32(i)=i)
__device__ __forceinline__ bool jax_keep(unsigned k1, unsigned i) {
  unsigned o0, o1;
  threefry2x32(0u, k1, 0u, i, o0, o1);
  unsigned bits = o0 ^ o1;
  float u = __uint_as_float((bits >> 9) | 0x3F800000u) - 1.0f;
  return u < 0.8f;
}

// ---------------- embedding + input dropout + mask ----------------
__global__ void embed_kernel(const int* __restrict__ tokens,
                             const int* __restrict__ lengths,
                             const float* __restrict__ emb,
                             _Float16* __restrict__ x) {
  unsigned i = blockIdx.x * 256u + threadIdx.x;
  if (i >= (unsigned)(B_ * T_ * E_)) return;
  int e = (int)(i & (E_ - 1));
  int t = (int)((i >> 8) & (T_ - 1));
  int b = (int)(i >> 17);
  int tok = tokens[b * T_ + t];
  float v = emb[tok * E_ + e];
  bool m = t < lengths[b];
  float xv = (m && jax_keep(1u, i)) ? (v * 1.25f) : 0.0f;
  x[i] = (_Float16)xv;
}

// ---------------- persistent bidirectional LSTM ----------------
__device__ __forceinline__ float sigm(float v) { return 1.0f / (1.0f + expf(-v)); }

__global__ __launch_bounds__(512) void lstm_kernel(
    const float* __restrict__ WxF, const float* __restrict__ WhF, const float* __restrict__ bF,
    const float* __restrict__ WxB, const float* __restrict__ WhB, const float* __restrict__ bB,
    const int* __restrict__ lengths,
    const _Float16* __restrict__ x,    // [B][T][E]
    _Float16* __restrict__ hbuf,       // [dir][2][B][H]
    float* __restrict__ out)           // [B][T][H]
{
  __shared__ _Float16 Wlds[32][1288];  // [col][k] K=1280 (+8 pad)
  __shared__ float zlds[128][36];
  __shared__ float bias_s[32];
  __shared__ int len_s[128];

  cg::grid_group grid = cg::this_grid();

  const int wg   = blockIdx.x;
  const int dir  = wg >> 7;           // 0 fwd, 1 bwd
  const int cb   = wg & 127;          // h-column block: cols [cb*8, cb*8+8)
  const int tid  = (int)threadIdx.x;
  const int lane = tid & 63;
  const int wv   = tid >> 6;          // wave 0..7

  const float* Wx = dir ? WxB : WxF;
  const float* Wh = dir ? WhB : WhF;
  const float* bias = dir ? bB : bF;
  _Float16* hb = hbuf + (size_t)dir * (2 * B_ * H_);

  // load W slice (f32 -> f16) : lds col c = gate(c>>3)*1024 + cb*8 + (c&7)
  for (int idx = tid; idx < KTOT * 32; idx += 512) {
    int k = idx >> 5, c = idx & 31;
    int wcol = ((c >> 3) << 10) + cb * 8 + (c & 7);
    float v = (k < E_) ? Wx[k * G_ + wcol] : Wh[(k - E_) * G_ + wcol];
    Wlds[c][k] = (_Float16)v;
  }
  if (tid < 32)  bias_s[tid] = bias[((tid >> 3) << 10) + cb * 8 + (tid & 7)];
  if (tid < B_)  len_s[tid] = lengths[tid];
  __syncthreads();

  // gate-phase mapping: thread -> (batch gb, h-sub-cols gj, gj+1)
  const int gb = tid >> 2;
  const int gj = (tid & 3) * 2;
  float creg0 = 0.f, creg1 = 0.f, hreg0 = 0.f, hreg1 = 0.f;

  // GEMM mapping
  const int mrow = (wv << 4) + (lane & 15);   // batch row for A-frag
  const int ksub = (lane >> 4) << 3;          // k-offset within 32-block
  const int c0   = lane & 15;                 // B-frag column within N-tile
  const _Float16* xbase = x + (size_t)mrow * T_ * E_;
  const _Float16* w0 = &Wlds[c0][0];
  const _Float16* w1 = &Wlds[16 + c0][0];

  int cur = 0;
#pragma unroll 1
  for (int s = 0; s < T_; ++s) {
    const int t = dir ? (T_ - 1 - s) : s;

    f32x4 acc0 = {0.f, 0.f, 0.f, 0.f}, acc1 = {0.f, 0.f, 0.f, 0.f};
    {
      const _Float16* xr = xbase + t * E_ + ksub;
#pragma unroll
      for (int kk = 0; kk < 8; ++kk) {       // x part: k = 0..255
        f16x8 a  = *(const f16x8*)(xr + kk * 32);
        f16x8 q0 = *(const f16x8*)(w0 + ksub + kk * 32);
        f16x8 q1 = *(const f16x8*)(w1 + ksub + kk * 32);
        acc0 = __builtin_amdgcn_mfma_f32_16x16x32_f16(a, q0, acc0, 0, 0, 0);
        acc1 = __builtin_amdgcn_mfma_f32_16x16x32_f16(a, q1, acc1, 0, 0, 0);
      }
      if (s > 0) {                            // h part: k = 256..1279
        const _Float16* hr = hb + (size_t)cur * (B_ * H_) + mrow * H_ + ksub;
#pragma unroll 8
        for (int kk = 0; kk < 32; ++kk) {
          f16x8 a  = *(const f16x8*)(hr + kk * 32);
          f16x8 q0 = *(const f16x8*)(w0 + E_ + ksub + kk * 32);
          f16x8 q1 = *(const f16x8*)(w1 + E_ + ksub + kk * 32);
          acc0 = __builtin_amdgcn_mfma_f32_16x16x32_f16(a, q0, acc0, 0, 0, 0);
          acc1 = __builtin_amdgcn_mfma_f32_16x16x32_f16(a, q1, acc1, 0, 0, 0);
        }
      }
    }
    // dump z tile to LDS. C layout: col = lane&15, row = (lane>>4)*4 + r
    {
      int r0 = (wv << 4) + ((lane >> 4) << 2);
#pragma unroll
      for (int r = 0; r < 4; ++r) {
        zlds[r0 + r][c0]      = acc0[r];
        zlds[r0 + r][16 + c0] = acc1[r];
      }
    }
    __syncthreads();
    // gates (f32, state in regs)
    {
      bool m = t < len_s[gb];
      float zi0 = zlds[gb][gj]      + bias_s[gj];
      float zf0 = zlds[gb][8 + gj]  + bias_s[8 + gj];
      float zg0 = zlds[gb][16 + gj] + bias_s[16 + gj];
      float zo0 = zlds[gb][24 + gj] + bias_s[24 + gj];
      float zi1 = zlds[gb][gj + 1]  + bias_s[gj + 1];
      float zf1 = zlds[gb][9 + gj]  + bias_s[9 + gj];
      float zg1 = zlds[gb][17 + gj] + bias_s[17 + gj];
      float zo1 = zlds[gb][25 + gj] + bias_s[25 + gj];

      float cn0 = sigm(zf0) * creg0 + sigm(zi0) * tanhf(zg0);
      float hn0 = sigm(zo0) * tanhf(cn0);
      float cn1 = sigm(zf1) * creg1 + sigm(zi1) * tanhf(zg1);
      float hn1 = sigm(zo1) * tanhf(cn1);
      if (m) { creg0 = cn0; hreg0 = hn0; creg1 = cn1; hreg1 = hn1; }
      float y0 = m ? hn0 : 0.f;
      float y1 = m ? hn1 : 0.f;

      _Float16* hw = hb + (size_t)(cur ^ 1) * (B_ * H_) + gb * H_ + cb * 8 + gj;
      hw[0] = (_Float16)hreg0;
      hw[1] = (_Float16)hreg1;

      float* op = out + ((size_t)gb * T_ + t) * H_ + cb * 8 + gj;
      if (s < 256) { op[0] = y0; op[1] = y1; }          // first writer
      else         { op[0] += y0; op[1] += y1; }        // second writer adds
    }
    grid.sync();
    cur ^= 1;
  }
}

// ---------------- output dropout (in place) ----------------
__global__ void outdrop_kernel(float* __restrict__ out) {
  const unsigned N = (unsigned)((size_t)B_ * T_ * H_);   // 67108864
  unsigned stride = gridDim.x * blockDim.x;
  for (unsigned i = blockIdx.x * blockDim.x + threadIdx.x; i < N; i += stride) {
    float v = out[i];
    out[i] = jax_keep(2u, i) ? (v * 1.25f) : 0.f;
  }
}

extern "C" void kernel_launch(void* const* d_in, const int* in_sizes, int n_in,
                              void* d_out, int out_size, void* d_ws, size_t ws_size,
                              hipStream_t stream) {
  (void)in_sizes; (void)n_in; (void)out_size; (void)ws_size;
  const int*   tokens  = (const int*)d_in[0];
  const int*   lengths = (const int*)d_in[1];
  const float* emb     = (const float*)d_in[2];
  const float* WxF     = (const float*)d_in[3];
  const float* WhF     = (const float*)d_in[4];
  const float* bF      = (const float*)d_in[5];
  const float* WxB     = (const float*)d_in[6];
  const float* WhB     = (const float*)d_in[7];
  const float* bB      = (const float*)d_in[8];
  float* out = (float*)d_out;

  _Float16* x    = (_Float16*)d_ws;
  _Float16* hbuf = (_Float16*)((char*)d_ws + (size_t)B_ * T_ * E_ * 2);

  embed_kernel<<<(B_ * T_ * E_ + 255) / 256, 256, 0, stream>>>(tokens, lengths, emb, x);

  void* args[] = { (void*)&WxF, (void*)&WhF, (void*)&bF,
                   (void*)&WxB, (void*)&WhB, (void*)&bB,
                   (void*)&lengths, (void*)&x, (void*)&hbuf, (void*)&out };
  hipLaunchCooperativeKernel((const void*)lstm_kernel, dim3(256), dim3(512),
                             args, 0, stream);

  outdrop_kernel<<<4096, 256, 0, stream>>>(out);
}

// Round 3
// 12106.922 us; speedup vs baseline: 1.8857x; 1.8857x over previous
//
#include <hip/hip_runtime.h>
#include <hip/hip_bf16.h>

#define B_ 128
#define T_ 512
#define E_ 256
#define H_ 1024
#define G_ 4096           // 4*H
#define KTOT 1280         // E + H

typedef _Float16 f16x8 __attribute__((ext_vector_type(8)));
typedef float f32x4 __attribute__((ext_vector_type(4)));

// ---------------- JAX threefry2x32 (exact) ----------------
__device__ __forceinline__ void threefry2x32(unsigned k0, unsigned k1,
                                             unsigned x0, unsigned x1,
                                             unsigned& o0, unsigned& o1) {
  unsigned k2 = k0 ^ k1 ^ 0x1BD11BDAu;
  unsigned v0 = x0 + k0, v1 = x1 + k1;
#define RND(r) { v0 += v1; v1 = (v1 << (r)) | (v1 >> (32 - (r))); v1 ^= v0; }
  RND(13) RND(15) RND(26) RND(6)   v0 += k1; v1 += k2 + 1u;
  RND(17) RND(29) RND(16) RND(24)  v0 += k2; v1 += k0 + 2u;
  RND(13) RND(15) RND(26) RND(6)   v0 += k0; v1 += k1 + 3u;
  RND(17) RND(29) RND(16) RND(24)  v0 += k1; v1 += k2 + 4u;
  RND(13) RND(15) RND(26) RND(6)   v0 += k2; v1 += k0 + 5u;
#undef RND
  o0 = v0; o1 = v1;
}

// JAX threefry_partitionable (default since 0.4.30), bit_width=32:
// bits(i) = b1 ^ b2 with (b1,b2) = threefry2x32(key, hi32(i)=0, lo32(i)=i)
__device__ __forceinline__ bool jax_keep(unsigned k1, unsigned i) {
  unsigned o0, o1;
  threefry2x32(0u, k1, 0u, i, o0, o1);
  unsigned bits = o0 ^ o1;
  float u = __uint_as_float((bits >> 9) | 0x3F800000u) - 1.0f;
  return u < 0.8f;
}

// ---------------- embedding + input dropout + mask ----------------
__global__ void embed_kernel(const int* __restrict__ tokens,
                             const int* __restrict__ lengths,
                             const float* __restrict__ emb,
                             _Float16* __restrict__ x) {
  unsigned i = blockIdx.x * 256u + threadIdx.x;
  if (i >= (unsigned)(B_ * T_ * E_)) return;
  int e = (int)(i & (E_ - 1));
  int t = (int)((i >> 8) & (T_ - 1));
  int b = (int)(i >> 17);
  int tok = tokens[b * T_ + t];
  float v = emb[tok * E_ + e];
  bool m = t < lengths[b];
  float xv = (m && jax_keep(1u, i)) ? (v * 1.25f) : 0.0f;
  x[i] = (_Float16)xv;
}

// ---------------- custom device-scope barriers ----------------
__device__ __forceinline__ void bar_arrive(unsigned* cnt, unsigned* gen, unsigned nwg) {
  __syncthreads();   // drains all waves' stores (vmcnt) before the release
  if (threadIdx.x == 0) {
    unsigned a = __hip_atomic_fetch_add(cnt, 1u, __ATOMIC_ACQ_REL, __HIP_MEMORY_SCOPE_AGENT);
    if (a == nwg - 1u) {
      __hip_atomic_store(cnt, 0u, __ATOMIC_RELAXED, __HIP_MEMORY_SCOPE_AGENT);
      __hip_atomic_fetch_add(gen, 1u, __ATOMIC_RELEASE, __HIP_MEMORY_SCOPE_AGENT);
    }
  }
}
__device__ __forceinline__ void bar_wait(unsigned* gen, unsigned target) {
  if (threadIdx.x == 0) {
    while (__hip_atomic_load(gen, __ATOMIC_ACQUIRE, __HIP_MEMORY_SCOPE_AGENT) < target)
      __builtin_amdgcn_s_sleep(2);
  }
  __syncthreads();
}

// ---------------- persistent bidirectional LSTM ----------------
__device__ __forceinline__ float sigm(float v) { return 1.0f / (1.0f + expf(-v)); }

__global__ __launch_bounds__(512) void lstm_kernel(
    const float* __restrict__ WxF, const float* __restrict__ WhF, const float* __restrict__ bF,
    const float* __restrict__ WxB, const float* __restrict__ WhB, const float* __restrict__ bB,
    const int* __restrict__ lengths,
    const _Float16* __restrict__ x,    // [B][T][E]
    _Float16* __restrict__ hbuf,       // [dir][2][B][H]
    unsigned* __restrict__ bars,       // barrier state (memset 0 per launch)
    float* __restrict__ out)           // [B][T][H]
{
  __shared__ _Float16 Wlds[32][1288];  // [col][k] K=1280 (+8 pad)
  __shared__ float zlds[128][36];
  __shared__ float bias_s[32];
  __shared__ int len_s[128];

  const int wg   = blockIdx.x;
  const int dir  = wg & 1;            // even wgs (even XCDs) = fwd, odd = bwd
  const int cb   = wg >> 1;           // h-column block: cols [cb*8, cb*8+8)
  const int tid  = (int)threadIdx.x;
  const int lane = tid & 63;
  const int wv   = tid >> 6;          // wave 0..7

  unsigned* cnt_d = bars + dir * 32;        // 128B-spaced lines
  unsigned* gen_d = bars + 64 + dir * 32;
  unsigned* cnt_g = bars + 128;
  unsigned* gen_g = bars + 160;

  const float* Wx = dir ? WxB : WxF;
  const float* Wh = dir ? WhB : WhF;
  const float* bias = dir ? bB : bF;
  _Float16* hb = hbuf + (size_t)dir * (2 * B_ * H_);

  // load W slice (f32 -> f16) : lds col c = gate(c>>3)*1024 + cb*8 + (c&7)
  for (int idx = tid; idx < KTOT * 32; idx += 512) {
    int k = idx >> 5, c = idx & 31;
    int wcol = ((c >> 3) << 10) + cb * 8 + (c & 7);
    float v = (k < E_) ? Wx[k * G_ + wcol] : Wh[(k - E_) * G_ + wcol];
    Wlds[c][k] = (_Float16)v;
  }
  if (tid < 32)  bias_s[tid] = bias[((tid >> 3) << 10) + cb * 8 + (tid & 7)];
  if (tid < B_)  len_s[tid] = lengths[tid];
  __syncthreads();

  // gate-phase mapping: thread -> (batch gb, h-sub-cols gj, gj+1)
  const int gb = tid >> 2;
  const int gj = (tid & 3) * 2;
  float creg0 = 0.f, creg1 = 0.f, hreg0 = 0.f, hreg1 = 0.f;

  // GEMM mapping
  const int mrow = (wv << 4) + (lane & 15);   // batch row for A-frag
  const int ksub = (lane >> 4) << 3;          // k-offset within 32-block
  const int c0   = lane & 15;                 // B-frag column within N-tile
  const _Float16* xbase = x + (size_t)mrow * T_ * E_;
  const _Float16* w0 = &Wlds[c0][0];
  const _Float16* w1 = &Wlds[16 + c0][0];

  int cur = 0;
#pragma unroll 1
  for (int s = 0; s < T_; ++s) {
    const int t = dir ? (T_ - 1 - s) : s;

    // one-time global rendezvous: all stores (s<256) before any add (s>=256)
    if (s == 256) { bar_arrive(cnt_g, gen_g, 256u); bar_wait(gen_g, 1u); }

    // prefetch out-RMW operands (stable post-midpoint), overlaps the h wait
    float* op = out + ((size_t)gb * T_ + t) * H_ + cb * 8 + gj;
    float oy0 = 0.f, oy1 = 0.f;
    if (s >= 256) { oy0 = op[0]; oy1 = op[1]; }

    // x-part GEMM: no dependency on h(s-1), runs before the barrier wait
    f32x4 acc0 = {0.f, 0.f, 0.f, 0.f}, acc1 = {0.f, 0.f, 0.f, 0.f};
    {
      const _Float16* xr = xbase + t * E_ + ksub;
#pragma unroll
      for (int kk = 0; kk < 8; ++kk) {       // k = 0..255
        f16x8 a  = *(const f16x8*)(xr + kk * 32);
        f16x8 q0 = *(const f16x8*)(w0 + ksub + kk * 32);
        f16x8 q1 = *(const f16x8*)(w1 + ksub + kk * 32);
        acc0 = __builtin_amdgcn_mfma_f32_16x16x32_f16(a, q0, acc0, 0, 0, 0);
        acc1 = __builtin_amdgcn_mfma_f32_16x16x32_f16(a, q1, acc1, 0, 0, 0);
      }
    }

    if (s > 0) {
      bar_wait(gen_d, (unsigned)s);           // h(s-1) published
      const _Float16* hr = hb + (size_t)cur * (B_ * H_) + mrow * H_ + ksub;
#pragma unroll
      for (int kk = 0; kk < 32; ++kk) {       // k = 256..1279
        f16x8 a  = *(const f16x8*)(hr + kk * 32);
        f16x8 q0 = *(const f16x8*)(w0 + E_ + ksub + kk * 32);
        f16x8 q1 = *(const f16x8*)(w1 + E_ + ksub + kk * 32);
        acc0 = __builtin_amdgcn_mfma_f32_16x16x32_f16(a, q0, acc0, 0, 0, 0);
        acc1 = __builtin_amdgcn_mfma_f32_16x16x32_f16(a, q1, acc1, 0, 0, 0);
      }
    }

    // dump z tile to LDS. C layout: col = lane&15, row = (lane>>4)*4 + r
    {
      int r0 = (wv << 4) + ((lane >> 4) << 2);
#pragma unroll
      for (int r = 0; r < 4; ++r) {
        zlds[r0 + r][c0]      = acc0[r];
        zlds[r0 + r][16 + c0] = acc1[r];
      }
    }
    __syncthreads();
    // gates (f32, state in regs)
    {
      bool m = t < len_s[gb];
      float zi0 = zlds[gb][gj]      + bias_s[gj];
      float zf0 = zlds[gb][8 + gj]  + bias_s[8 + gj];
      float zg0 = zlds[gb][16 + gj] + bias_s[16 + gj];
      float zo0 = zlds[gb][24 + gj] + bias_s[24 + gj];
      float zi1 = zlds[gb][gj + 1]  + bias_s[gj + 1];
      float zf1 = zlds[gb][9 + gj]  + bias_s[9 + gj];
      float zg1 = zlds[gb][17 + gj] + bias_s[17 + gj];
      float zo1 = zlds[gb][25 + gj] + bias_s[25 + gj];

      float cn0 = sigm(zf0) * creg0 + sigm(zi0) * tanhf(zg0);
      float hn0 = sigm(zo0) * tanhf(cn0);
      float cn1 = sigm(zf1) * creg1 + sigm(zi1) * tanhf(zg1);
      float hn1 = sigm(zo1) * tanhf(cn1);
      if (m) { creg0 = cn0; hreg0 = hn0; creg1 = cn1; hreg1 = hn1; }
      float y0 = m ? hn0 : 0.f;
      float y1 = m ? hn1 : 0.f;

      _Float16* hw = hb + (size_t)(cur ^ 1) * (B_ * H_) + gb * H_ + cb * 8 + gj;
      hw[0] = (_Float16)hreg0;
      hw[1] = (_Float16)hreg1;

      if (s < 256) { op[0] = y0;       op[1] = y1; }        // first writer
      else         { op[0] = oy0 + y0; op[1] = oy1 + y1; }  // second writer adds
    }
    if (s < T_ - 1) bar_arrive(cnt_d, gen_d, 128u);         // publish h(s)
    cur ^= 1;
  }
}

// ---------------- output dropout (in place) ----------------
__global__ void outdrop_kernel(float* __restrict__ out) {
  const unsigned N = (unsigned)((size_t)B_ * T_ * H_);   // 67108864
  unsigned stride = gridDim.x * blockDim.x;
  for (unsigned i = blockIdx.x * blockDim.x + threadIdx.x; i < N; i += stride) {
    float v = out[i];
    out[i] = jax_keep(2u, i) ? (v * 1.25f) : 0.f;
  }
}

extern "C" void kernel_launch(void* const* d_in, const int* in_sizes, int n_in,
                              void* d_out, int out_size, void* d_ws, size_t ws_size,
                              hipStream_t stream) {
  (void)in_sizes; (void)n_in; (void)out_size; (void)ws_size;
  const int*   tokens  = (const int*)d_in[0];
  const int*   lengths = (const int*)d_in[1];
  const float* emb     = (const float*)d_in[2];
  const float* WxF     = (const float*)d_in[3];
  const float* WhF     = (const float*)d_in[4];
  const float* bF      = (const float*)d_in[5];
  const float* WxB     = (const float*)d_in[6];
  const float* WhB     = (const float*)d_in[7];
  const float* bB      = (const float*)d_in[8];
  float* out = (float*)d_out;

  _Float16* x    = (_Float16*)d_ws;
  _Float16* hbuf = (_Float16*)((char*)d_ws + (size_t)B_ * T_ * E_ * 2);
  unsigned* bars = (unsigned*)((char*)d_ws + 34603008);   // 1KB barrier region

  hipMemsetAsync(bars, 0, 1024, stream);

  embed_kernel<<<(B_ * T_ * E_ + 255) / 256, 256, 0, stream>>>(tokens, lengths, emb, x);

  void* args[] = { (void*)&WxF, (void*)&WhF, (void*)&bF,
                   (void*)&WxB, (void*)&WhB, (void*)&bB,
                   (void*)&lengths, (void*)&x, (void*)&hbuf, (void*)&bars, (void*)&out };
  hipLaunchCooperativeKernel((const void*)lstm_kernel, dim3(256), dim3(512),
                             args, 0, stream);

  outdrop_kernel<<<4096, 256, 0, stream>>>(out);
}